// Round 9
// baseline (470.281 us; speedup 1.0000x reference)
//
#include <hip/hip_runtime.h>
#include <hip/hip_bf16.h>
#include <cstdint>

// ---------------------------------------------------------------------------
// GraphSAGE inference. bf16 GEMM plane (MFMA, async LDS staging); fp8 e4m3
// aggregation tables; node-range-binned CSR build.
// Round 16: structural consolidation.
//  - gemm_big512 reverted to R7 512-thr config (R8's 1024-thr regressed;
//    launch_bounds(1024,8) forced a 64-VGPR budget).
//  - CSR chain fused: bin -> scan_gcnt(1 wave) -> csr_bucket (hist + LDS
//    512-scan + row_start + scatter in ONE kernel). deg array eliminated.
//  - gemm_l2: both column-halves (Sself|Tb) in one TN=128 kernel; h1b read
//    once. conv_x + wt_all merged into one dispatch (block-range split).
//  - agg256 accepted at its random-gather LLC floor (2.7 TB/s invariant).
// ---------------------------------------------------------------------------

typedef __attribute__((ext_vector_type(8))) short  frag_ab;  // 8 bf16
typedef __attribute__((ext_vector_type(4))) float  f32x4;
typedef __attribute__((ext_vector_type(2))) float  vf2;

#define BIN_T 4096      // edges per partition tile (512 thr x 8)
#define RSHIFT 9        // 512-node bucket ranges
#define RW 512

__device__ __forceinline__ unsigned short f2b(float f) {
    __hip_bfloat16 h = __float2bfloat16(f);
    return *reinterpret_cast<unsigned short*>(&h);
}
__device__ __forceinline__ unsigned char f2p8(float f) {
    int p = __builtin_amdgcn_cvt_pk_fp8_f32(f, f, 0, false);
    return (unsigned char)(p & 0xff);
}
// accumulate 8 bf16 (as uint4) into 4 packed-f32 pairs
__device__ __forceinline__ void acc8_v(vf2* a, uint4 v) {
    vf2 t0; t0.x = __uint_as_float(v.x << 16); t0.y = __uint_as_float(v.x & 0xffff0000u);
    vf2 t1; t1.x = __uint_as_float(v.y << 16); t1.y = __uint_as_float(v.y & 0xffff0000u);
    vf2 t2; t2.x = __uint_as_float(v.z << 16); t2.y = __uint_as_float(v.z & 0xffff0000u);
    vf2 t3; t3.x = __uint_as_float(v.w << 16); t3.y = __uint_as_float(v.w & 0xffff0000u);
    a[0] += t0; a[1] += t1; a[2] += t2; a[3] += t3;
}
// accumulate 16 fp8 (as uint4) into 8 packed-f32 pairs via HW cvt
__device__ __forceinline__ void acc16p_v(vf2* a, uint4 v) {
    a[0] += __builtin_amdgcn_cvt_pk_f32_fp8(v.x, false);
    a[1] += __builtin_amdgcn_cvt_pk_f32_fp8(v.x, true);
    a[2] += __builtin_amdgcn_cvt_pk_f32_fp8(v.y, false);
    a[3] += __builtin_amdgcn_cvt_pk_f32_fp8(v.y, true);
    a[4] += __builtin_amdgcn_cvt_pk_f32_fp8(v.z, false);
    a[5] += __builtin_amdgcn_cvt_pk_f32_fp8(v.z, true);
    a[6] += __builtin_amdgcn_cvt_pk_f32_fp8(v.w, false);
    a[7] += __builtin_amdgcn_cvt_pk_f32_fp8(v.w, true);
}

// async global->LDS, 16B per lane; lds base wave-uniform (HW adds lane*16)
__device__ __forceinline__ void gl_lds16(const void* g, void* l) {
    __builtin_amdgcn_global_load_lds(
        (const __attribute__((address_space(1))) unsigned int*)g,
        (__attribute__((address_space(3))) unsigned int*)l, 16, 0, 0);
}

// ---------------- CSR build: node-range binning ----------------
__global__ __launch_bounds__(512) void bin_edges(
    const int* __restrict__ src, const int* __restrict__ dst,
    int* __restrict__ bdst, int* __restrict__ bsrc,
    int* __restrict__ gcnt, int E, int cap) {
    __shared__ int lds_d[BIN_T];
    __shared__ int lds_s[BIN_T];
    __shared__ unsigned short lds_b[BIN_T];
    __shared__ int hist[8][128];
    __shared__ int cur[8][128];
    __shared__ int tot[128], scn[128], pref[128], gbase[128];

    const int tid = threadIdx.x;
    const int w = tid >> 6;
    const int e0 = blockIdx.x * BIN_T;
    const int base = e0 + tid * 8;

    int d[8], sv[8], bk[8];
    if (e0 + BIN_T <= E) {
        int4 a0 = *reinterpret_cast<const int4*>(dst + base);
        int4 a1 = *reinterpret_cast<const int4*>(dst + base + 4);
        int4 b0 = *reinterpret_cast<const int4*>(src + base);
        int4 b1 = *reinterpret_cast<const int4*>(src + base + 4);
        d[0] = a0.x; d[1] = a0.y; d[2] = a0.z; d[3] = a0.w;
        d[4] = a1.x; d[5] = a1.y; d[6] = a1.z; d[7] = a1.w;
        sv[0] = b0.x; sv[1] = b0.y; sv[2] = b0.z; sv[3] = b0.w;
        sv[4] = b1.x; sv[5] = b1.y; sv[6] = b1.z; sv[7] = b1.w;
#pragma unroll
        for (int j = 0; j < 8; j++) bk[j] = (int)((unsigned)d[j] >> RSHIFT);
    } else {
#pragma unroll
        for (int j = 0; j < 8; j++) {
            int e = base + j;
            if (e < E) {
                d[j] = dst[e]; sv[j] = src[e];
                bk[j] = (int)((unsigned)d[j] >> RSHIFT);
            } else {
                d[j] = 0; sv[j] = 0; bk[j] = -1;
            }
        }
    }

    // zero histograms
    for (int i = tid; i < 8 * 128; i += 512) ((int*)hist)[i] = 0;
    __syncthreads();
    // per-wave LDS histogram (contention ~ BIN_T/8/98 ~= 5)
#pragma unroll
    for (int j = 0; j < 8; j++)
        if (bk[j] >= 0) atomicAdd(&hist[w][bk[j]], 1);
    __syncthreads();
    // bucket totals + exclusive prefix (Hillis-Steele over 128)
    if (tid < 128) {
        int t = 0;
#pragma unroll
        for (int w2 = 0; w2 < 8; w2++) t += hist[w2][tid];
        tot[tid] = t; scn[tid] = t;
    }
    __syncthreads();
#pragma unroll
    for (int off = 1; off < 128; off <<= 1) {
        int v = 0;
        if (tid < 128 && tid >= off) v = scn[tid - off];
        __syncthreads();
        if (tid < 128 && tid >= off) scn[tid] += v;
        __syncthreads();
    }
    if (tid < 128) {
        pref[tid] = scn[tid] - tot[tid];
        gbase[tid] = atomicAdd(&gcnt[tid], tot[tid]);
        int b0 = pref[tid];
#pragma unroll
        for (int w2 = 0; w2 < 8; w2++) { cur[w2][tid] = b0; b0 += hist[w2][tid]; }
    }
    __syncthreads();
    // ranked placement into LDS
#pragma unroll
    for (int j = 0; j < 8; j++) {
        if (bk[j] >= 0) {
            int pos = atomicAdd(&cur[w][bk[j]], 1);
            lds_d[pos] = d[j];
            lds_s[pos] = sv[j];
            lds_b[pos] = (unsigned short)bk[j];
        }
    }
    __syncthreads();
    // coalesced flush
    const int nv = scn[127];
    for (int i = tid; i < nv; i += 512) {
        int b = lds_b[i];
        int off = gbase[b] + (i - pref[b]);
        bdst[(size_t)b * cap + off] = lds_d[i];
        bsrc[(size_t)b * cap + off] = lds_s[i];
    }
}

// One wave: exclusive scan of gcnt[128] -> gbase[128]; row_start[N] = E.
__global__ void scan_gcnt(const int* __restrict__ gcnt, int* __restrict__ gbase,
                          int* __restrict__ row_start, int N, int E) {
    const int lane = threadIdx.x;  // 64
    int v0 = gcnt[lane];
    int v1 = gcnt[64 + lane];
    int s0 = v0;
#pragma unroll
    for (int off = 1; off < 64; off <<= 1) { int x = __shfl_up(s0, off); if (lane >= off) s0 += x; }
    int tot0 = __shfl(s0, 63);
    int s1 = v1;
#pragma unroll
    for (int off = 1; off < 64; off <<= 1) { int x = __shfl_up(s1, off); if (lane >= off) s1 += x; }
    gbase[lane] = s0 - v0;
    gbase[64 + lane] = tot0 + s1 - v1;
    if (lane == 0) row_start[N] = E;
}

// Fused per-bucket: histogram -> 512-entry LDS scan -> row_start write ->
// scatter into csr (bucket-private ~65KB span, L2 write-combined).
__global__ __launch_bounds__(256) void csr_bucket(
    const int* __restrict__ bdst, const int* __restrict__ bsrc,
    const int* __restrict__ gcnt, const int* __restrict__ gbase,
    int* __restrict__ row_start, int* __restrict__ csr, int cap, int N) {
    const int b = blockIdx.x;
    const int cnt = gcnt[b];
    const int base = gbase[b];
    const int v0 = b << RSHIFT;
    __shared__ int h[RW];
    __shared__ int scn[RW];
    __shared__ int cur[RW];
    for (int k = threadIdx.x; k < RW; k += 256) h[k] = 0;
    __syncthreads();
    const int* bd = bdst + (size_t)b * cap;
    for (int i = threadIdx.x; i < cnt; i += 256)
        atomicAdd(&h[bd[i] & (RW - 1)], 1);
    __syncthreads();
    for (int k = threadIdx.x; k < RW; k += 256) scn[k] = h[k];
    __syncthreads();
    // inclusive Hillis-Steele over 512 with 256 threads (2 elems/thread)
    const int k0 = threadIdx.x, k1 = threadIdx.x + 256;
#pragma unroll
    for (int off = 1; off < RW; off <<= 1) {
        int t0 = (k0 >= off) ? scn[k0 - off] : 0;
        int t1 = (k1 >= off) ? scn[k1 - off] : 0;
        __syncthreads();
        scn[k0] += t0;
        scn[k1] += t1;
        __syncthreads();
    }
    for (int k = threadIdx.x; k < RW; k += 256) {
        int ex = base + scn[k] - h[k];     // exclusive prefix
        cur[k] = ex;
        int node = v0 + k;
        if (node < N) row_start[node] = ex;
    }
    __syncthreads();
    const int* bs = bsrc + (size_t)b * cap;
    for (int i = threadIdx.x; i < cnt; i += 256) {
        int dd = bd[i];
        int ss = bs[i];
        int pos = atomicAdd(&cur[dd & (RW - 1)], 1);
        csr[pos] = ss;
    }
}

// ---------------- conversions (merged conv_x + wt_all) ----------------
// Blocks [0, nConv): x -> bf16 + fp8 (+ zero rows of both fp8 tables).
// Blocks [nConv, nConv+1152): weight transposes.
__global__ __launch_bounds__(256) void conv_wt_kernel(
    const float* __restrict__ in, unsigned short* __restrict__ outb,
    unsigned char* __restrict__ outp, unsigned char* __restrict__ outp2, int n4, int nConv,
    const float* __restrict__ Ws0, const float* __restrict__ Wn0,
    const float* __restrict__ Ws1, const float* __restrict__ Wn1,
    const float* __restrict__ Ws2, const float* __restrict__ Wn2,
    unsigned short* __restrict__ Wt0, unsigned short* __restrict__ Wt1,
    unsigned short* __restrict__ Wt2) {
    if (blockIdx.x < (unsigned)nConv) {
        int i = blockIdx.x * 256 + threadIdx.x;
        if (blockIdx.x == 0 && threadIdx.x < 64) {
            *reinterpret_cast<unsigned int*>(outp  + (size_t)n4 * 4 + threadIdx.x * 4) = 0u;
            *reinterpret_cast<unsigned int*>(outp2 + (size_t)n4 * 4 + threadIdx.x * 4) = 0u;
        }
        if (i >= n4) return;
        float4 v = *reinterpret_cast<const float4*>(in + (size_t)i * 4);
        ushort4 ob = { f2b(v.x), f2b(v.y), f2b(v.z), f2b(v.w) };
        *reinterpret_cast<ushort4*>(outb + (size_t)i * 4) = ob;
        int p0 = __builtin_amdgcn_cvt_pk_fp8_f32(v.x, v.y, 0, false);
        int p1 = __builtin_amdgcn_cvt_pk_fp8_f32(v.z, v.w, 0, false);
        unsigned int packed = (unsigned int)(p0 & 0xffff) | ((unsigned int)p1 << 16);
        *reinterpret_cast<unsigned int*>(outp + (size_t)i * 4) = packed;
        return;
    }
    int b = blockIdx.x - nConv;
    const float* W; unsigned short* Wt; int Nn, koff, Ktot, noff, idx;
    if (b < 1024) {
        int seg = b >> 8; idx = (b & 255) * 256 + threadIdx.x;
        Nn = 256; Ktot = 512; noff = 0;
        if (seg == 0)      { W = Ws0; Wt = Wt0; koff = 0;   }
        else if (seg == 1) { W = Wn0; Wt = Wt0; koff = 256; }
        else if (seg == 2) { W = Ws1; Wt = Wt1; koff = 0;   }
        else               { W = Wn1; Wt = Wt1; koff = 256; }
    } else {
        int seg = (b - 1024) >> 6; idx = ((b - 1024) & 63) * 256 + threadIdx.x;
        Nn = 64; Ktot = 256; koff = 0;
        if (seg == 0) { W = Ws2; Wt = Wt2; noff = 0;  }
        else          { W = Wn2; Wt = Wt2; noff = 64; }
    }
    int k = idx / Nn, n = idx - k * Nn;
    Wt[(size_t)(n + noff) * Ktot + koff + k] = f2b(W[(size_t)idx]);
}

// ---------------- aggregation ----------------
// fp8 rows (256B). One node per 16-lane quarter; lane owns 16B slice.
// Sequential edge stream, 6-deep modulo-scheduled prefetch; OOB -> zero row.
__global__ __launch_bounds__(256) void agg256_fp8(
    const unsigned char* __restrict__ hsrc, const int* __restrict__ row_start,
    const int* __restrict__ csr, unsigned short* __restrict__ out, int n, int zrow) {
    int wv = (blockIdx.x * blockDim.x + threadIdx.x) >> 6;
    int lane = threadIdx.x & 63;
    if (wv * 4 >= n) return;
    const int q  = lane >> 4;
    const int li = lane & 15;
    const int node = wv * 4 + q;
    const bool act = node < n;
    int s0 = act ? row_start[node] : 0;
    int s1 = act ? row_start[node + 1] : 0;
    int deg = s1 - s0;
    int nmax = deg;
    nmax = max(nmax, __shfl_xor(nmax, 16));
    nmax = max(nmax, __shfl_xor(nmax, 32));

    const size_t lioff = (size_t)li * 16;
    vf2 a[8];
#pragma unroll
    for (int k = 0; k < 8; k++) a[k] = (vf2)(0.f);

#define LD256(vv, k) { int _e = s0 + (k); \
    int _ci = csr[max(min(_e, s1 - 1), 0)]; \
    int _ii = ((k) < deg) ? _ci : zrow; \
    vv = *reinterpret_cast<const uint4*>(hsrc + (size_t)_ii * 256 + lioff); }

    uint4 v0, v1, v2, v3, v4, v5;
    LD256(v0, 0); LD256(v1, 1); LD256(v2, 2);
    LD256(v3, 3); LD256(v4, 4); LD256(v5, 5);
    for (int b = 0; b < nmax; b += 6) {
        acc16p_v(a, v0); LD256(v0, b + 6);
        acc16p_v(a, v1); LD256(v1, b + 7);
        acc16p_v(a, v2); LD256(v2, b + 8);
        acc16p_v(a, v3); LD256(v3, b + 9);
        acc16p_v(a, v4); LD256(v4, b + 10);
        acc16p_v(a, v5); LD256(v5, b + 11);
    }
#undef LD256

    if (act) {
        float sc = 1.0f / (float)max(deg, 1);
        uint4 o0, o1;
        o0.x = ((unsigned)f2b(a[0].y * sc) << 16) | f2b(a[0].x * sc);
        o0.y = ((unsigned)f2b(a[1].y * sc) << 16) | f2b(a[1].x * sc);
        o0.z = ((unsigned)f2b(a[2].y * sc) << 16) | f2b(a[2].x * sc);
        o0.w = ((unsigned)f2b(a[3].y * sc) << 16) | f2b(a[3].x * sc);
        o1.x = ((unsigned)f2b(a[4].y * sc) << 16) | f2b(a[4].x * sc);
        o1.y = ((unsigned)f2b(a[5].y * sc) << 16) | f2b(a[5].x * sc);
        o1.z = ((unsigned)f2b(a[6].y * sc) << 16) | f2b(a[6].x * sc);
        o1.w = ((unsigned)f2b(a[7].y * sc) << 16) | f2b(a[7].x * sc);
        *reinterpret_cast<uint4*>(out + (size_t)node * 256 + li * 16) = o0;
        *reinterpret_cast<uint4*>(out + (size_t)node * 256 + li * 16 + 8) = o1;
    }
}

// h2[v][:] = Sself[v][:] + mean_{s in N(v)} Tb[s][:] + b2 ; Tb bf16 64-wide.
// One node per 8-lane group; lane owns 16B (8 bf16) slice; 6-deep prefetch.
// OOB edges zeroed in-register. h2 is a final sink -> nontemporal store.
__global__ __launch_bounds__(256) void agg64_final(
    const unsigned short* __restrict__ t, const int* __restrict__ row_start,
    const int* __restrict__ csr, const float* __restrict__ Sself,
    const float* __restrict__ b2, float* __restrict__ h2, int n) {
    int wv = (blockIdx.x * blockDim.x + threadIdx.x) >> 6;
    int lane = threadIdx.x & 63;
    if (wv * 8 >= n) return;
    const int g  = lane >> 3;
    const int li = lane & 7;
    const int node = wv * 8 + g;
    const bool act = node < n;
    int s0 = act ? row_start[node] : 0;
    int s1 = act ? row_start[node + 1] : 0;
    int deg = s1 - s0;
    int nmax = deg;
    nmax = max(nmax, __shfl_xor(nmax, 8));
    nmax = max(nmax, __shfl_xor(nmax, 16));
    nmax = max(nmax, __shfl_xor(nmax, 32));

    const size_t lioff = (size_t)li * 8;   // shorts
    vf2 a[4];
#pragma unroll
    for (int k = 0; k < 4; k++) a[k] = (vf2)(0.f);

#define LD64(vv, k) { int _e = s0 + (k); \
    int _ci = csr[max(min(_e, s1 - 1), 0)]; \
    vv = make_uint4(0u, 0u, 0u, 0u); \
    if ((k) < deg) \
        vv = *reinterpret_cast<const uint4*>(t + (size_t)_ci * 64 + lioff); }

    uint4 v0, v1, v2, v3, v4, v5;
    LD64(v0, 0); LD64(v1, 1); LD64(v2, 2);
    LD64(v3, 3); LD64(v4, 4); LD64(v5, 5);
    for (int b = 0; b < nmax; b += 6) {
        acc8_v(a, v0); LD64(v0, b + 6);
        acc8_v(a, v1); LD64(v1, b + 7);
        acc8_v(a, v2); LD64(v2, b + 8);
        acc8_v(a, v3); LD64(v3, b + 9);
        acc8_v(a, v4); LD64(v4, b + 10);
        acc8_v(a, v5); LD64(v5, b + 11);
    }
#undef LD64

    if (act) {
        float sc = 1.0f / (float)max(deg, 1);
        float4 s0v = *reinterpret_cast<const float4*>(Sself + (size_t)node * 64 + li * 8);
        float4 s1v = *reinterpret_cast<const float4*>(Sself + (size_t)node * 64 + li * 8 + 4);
        float4 bb0 = *reinterpret_cast<const float4*>(b2 + li * 8);
        float4 bb1 = *reinterpret_cast<const float4*>(b2 + li * 8 + 4);
        f32x4 o0, o1;
        o0.x = s0v.x + a[0].x * sc + bb0.x; o0.y = s0v.y + a[0].y * sc + bb0.y;
        o0.z = s0v.z + a[1].x * sc + bb0.z; o0.w = s0v.w + a[1].y * sc + bb0.w;
        o1.x = s1v.x + a[2].x * sc + bb1.x; o1.y = s1v.y + a[2].y * sc + bb1.y;
        o1.z = s1v.z + a[3].x * sc + bb1.z; o1.w = s1v.w + a[3].y * sc + bb1.w;
        __builtin_nontemporal_store(o0, reinterpret_cast<f32x4*>(h2 + (size_t)node * 64 + li * 8));
        __builtin_nontemporal_store(o1, reinterpret_cast<f32x4*>(h2 + (size_t)node * 64 + li * 8 + 4));
    }
}

// ---------------- big GEMM: 128x256 row-stripe, 512 threads ----------------
// C[M,256] = relu( [A|G] @ Wt^T + bias ); A,G bf16 [M][256], Wt bf16 [256][512].
#define BTM 128
#define BTN 256
#define BTK 32

__global__ __launch_bounds__(512, 4) void gemm_big512(
    const unsigned short* __restrict__ A, const unsigned short* __restrict__ G,
    const unsigned short* __restrict__ Wt, const float* __restrict__ bias,
    float* __restrict__ outF, unsigned short* __restrict__ outB,
    unsigned char* __restrict__ outP, int M) {
    __shared__ unsigned short Asb[BTM][BTK];   // 8 KB, lane-linear for lds-dma
    __shared__ unsigned short Bsb[BTN][BTK];   // 16 KB

    const int tid = threadIdx.x;
    const int row0 = blockIdx.x * BTM;
    const int w = tid >> 6, lane = tid & 63;
    const int mw = (w & 1) * 64;       // wave m-offset (2 m-groups)
    const int nw = (w >> 1) * 64;      // wave n-offset (4 n-groups)
    const int lm = lane & 15, lq = lane >> 4;
    const int lr = lane >> 2;          // 0..15
    const int lc = (lane & 3) * 8;     // 0/8/16/24 shorts

    f32x4 acc[4][4];
#pragma unroll
    for (int i = 0; i < 4; i++)
#pragma unroll
        for (int j = 0; j < 4; j++) acc[i][j] = (f32x4)(0.f);

    for (int k0 = 0; k0 < 512; k0 += BTK) {
        const unsigned short* __restrict__ Ap = (k0 >= 256) ? G : A;
        const int kl = k0 & 255;
        {
            int gr = row0 + w * 16 + lr;
            if (gr < M)
                gl_lds16(Ap + (size_t)gr * 256 + kl + lc, &Asb[w * 16][0]);
        }
#pragma unroll
        for (int h = 0; h < 2; ++h) {
            int gn = w * 32 + h * 16 + lr;
            gl_lds16(Wt + (size_t)gn * 512 + k0 + lc, &Bsb[w * 32 + h * 16][0]);
        }
        __syncthreads();

        frag_ab a[4], b[4];
#pragma unroll
        for (int i = 0; i < 4; i++)
            a[i] = *reinterpret_cast<const frag_ab*>(&Asb[mw + i * 16 + lm][lq * 8]);
#pragma unroll
        for (int j = 0; j < 4; j++)
            b[j] = *reinterpret_cast<const frag_ab*>(&Bsb[nw + j * 16 + lm][lq * 8]);
#pragma unroll
        for (int i = 0; i < 4; i++)
#pragma unroll
            for (int j = 0; j < 4; j++)
                acc[i][j] = __builtin_amdgcn_mfma_f32_16x16x32_bf16(a[i], b[j], acc[i][j], 0, 0, 0);
        __syncthreads();
    }

#pragma unroll
    for (int i = 0; i < 4; i++) {
#pragma unroll
        for (int j = 0; j < 4; j++) {
            int cg = nw + j * 16 + lm;
#pragma unroll
            for (int r = 0; r < 4; r++) {
                int rg = row0 + mw + i * 16 + lq * 4 + r;
                if (rg >= M) continue;
                float v = acc[i][j][r] + bias[cg];
                v = fmaxf(v, 0.f);
                outB[(size_t)rg * 256 + cg] = f2b(v);
                if (outF) __builtin_nontemporal_store(v, &outF[(size_t)rg * 256 + cg]);  // h1 = final sink
                if (outP) outP[(size_t)rg * 256 + cg] = f2p8(v);
            }
        }
    }
}

// ---------------- layer-2 GEMM: TN=128, both halves in one pass ------------
// Sself (cols 0-63, fp32) | Tb (cols 64-127, bf16). h1b read ONCE.
#define TM 128

__global__ __launch_bounds__(256) void gemm_l2(
    const unsigned short* __restrict__ A, const unsigned short* __restrict__ Wt,
    float* __restrict__ outF, unsigned short* __restrict__ outB, int M) {
    __shared__ unsigned short Asb[128][32];    // 8 KB
    __shared__ unsigned short Bsb[128][32];    // 8 KB

    const int tid = threadIdx.x;
    const int row0 = blockIdx.x * TM;
    const int w = tid >> 6, lane = tid & 63;
    const int mw = (w & 1) * 64;
    const int nw = (w >> 1) * 64;
    const int lm = lane & 15, lq = lane >> 4;
    const int lr = lane >> 2;
    const int lc = (lane & 3) * 8;

    f32x4 acc[4][4];
#pragma unroll
    for (int i = 0; i < 4; i++)
#pragma unroll
        for (int j = 0; j < 4; j++) acc[i][j] = (f32x4)(0.f);

    for (int k0 = 0; k0 < 256; k0 += 32) {
#pragma unroll
        for (int h = 0; h < 2; ++h) {
            int r16 = w * 32 + h * 16;
            int gr = row0 + r16 + lr;
            if (gr < M)
                gl_lds16(A + (size_t)gr * 256 + k0 + lc, &Asb[r16][0]);
        }
#pragma unroll
        for (int h = 0; h < 2; ++h) {
            int n16 = w * 32 + h * 16;
            int gn = n16 + lr;
            gl_lds16(Wt + (size_t)gn * 256 + k0 + lc, &Bsb[n16][0]);
        }
        __syncthreads();

        frag_ab a[4], b[4];
#pragma unroll
        for (int i = 0; i < 4; i++)
            a[i] = *reinterpret_cast<const frag_ab*>(&Asb[mw + i * 16 + lm][lq * 8]);
#pragma unroll
        for (int j = 0; j < 4; j++)
            b[j] = *reinterpret_cast<const frag_ab*>(&Bsb[nw + j * 16 + lm][lq * 8]);
#pragma unroll
        for (int i = 0; i < 4; i++)
#pragma unroll
            for (int j = 0; j < 4; j++)
                acc[i][j] = __builtin_amdgcn_mfma_f32_16x16x32_bf16(a[i], b[j], acc[i][j], 0, 0, 0);
        __syncthreads();
    }

#pragma unroll
    for (int i = 0; i < 4; i++) {
#pragma unroll
        for (int j = 0; j < 4; j++) {
            int cg = nw + j * 16 + lm;   // 0..127
#pragma unroll
            for (int r = 0; r < 4; r++) {
                int rg = row0 + mw + i * 16 + lq * 4 + r;
                if (rg >= M) continue;
                float v = acc[i][j][r];
                if (cg < 64) outF[(size_t)rg * 64 + cg] = v;
                else         outB[(size_t)rg * 64 + (cg - 64)] = f2b(v);
            }
        }
    }
}

// ---------------------------------------------------------------------------
extern "C" void kernel_launch(void* const* d_in, const int* in_sizes, int n_in,
                              void* d_out, int out_size, void* d_ws, size_t ws_size,
                              hipStream_t stream) {
    const float* x   = (const float*)d_in[0];
    const int*   src = (const int*)d_in[1];
    const int*   dst = (const int*)d_in[2];
    const float* Ws0 = (const float*)d_in[3];
    const float* Wn0 = (const float*)d_in[4];
    const float* b0  = (const float*)d_in[5];
    const float* Ws1 = (const float*)d_in[6];
    const float* Wn1 = (const float*)d_in[7];
    const float* b1  = (const float*)d_in[8];
    const float* Ws2 = (const float*)d_in[9];
    const float* Wn2 = (const float*)d_in[10];
    const float* b2  = (const float*)d_in[11];

    const int N = in_sizes[0] / 256;   // 50000
    const int E = in_sizes[1];         // 1600000

    float* out = (float*)d_out;
    float* h2 = out;                       // N x 64  (output 0)
    float* h1 = out + (size_t)N * 64;      // N x 256 (output 1, fp32)

    const int nbuk = (N + RW - 1) >> RSHIFT;              // 98
    const int cap  = (E + nbuk - 1) / nbuk + 2048;        // mean + ~16 sigma

    // ---- workspace layout ----
    char* w = (char*)d_ws;
    auto align16 = [](char* p) { return (char*)(((uintptr_t)p + 15) & ~(uintptr_t)15); };
    int* gcnt      = (int*)w;  w += 128 * 4;
    int* gbase     = (int*)w;  w += 128 * 4;
    int* row_start = (int*)w;  w += (size_t)(N + 1) * 4;
    int* csr       = (int*)w;  w += (size_t)E * 4;
    int* bdst      = (int*)w;  w += (size_t)nbuk * cap * 4;
    int* bsrc      = (int*)w;  w += (size_t)nbuk * cap * 4;
    w = align16(w);
    unsigned short* Wt0   = (unsigned short*)w; w += (size_t)256 * 512 * 2;
    unsigned short* Wt1   = (unsigned short*)w; w += (size_t)256 * 512 * 2;
    unsigned short* Wt2   = (unsigned short*)w; w += (size_t)128 * 256 * 2;  // [Ws2t;Wn2t]
    w = align16(w);
    unsigned short* xb    = (unsigned short*)w; w += (size_t)(N + 1) * 256 * 2;
    unsigned short* A1b   = (unsigned short*)w; w += (size_t)N * 256 * 2;
    unsigned short* H0b   = (unsigned short*)w; w += (size_t)(N + 1) * 256 * 2;
    unsigned short* h1b   = (unsigned short*)w; w += (size_t)(N + 1) * 256 * 2;
    // dead-region aliases (zero extra workspace):
    unsigned char* x8  = (unsigned char*)H0b;  // dead once gemm0 writes H0b
    unsigned char* H08 = (unsigned char*)h1b;  // consumed by agg#2 before gemm1 writes h1b
    unsigned short* Tb    = xb;                // xb dead after gemm0
    float*          Sself = (float*)A1b;       // A1b dead after gemm1

    // ---- CSR build: bin -> scan -> fused bucket (hist+scan+rowstart+scatter)
    hipMemsetAsync(gcnt, 0, 128 * 4, stream);
    bin_edges<<<(E + BIN_T - 1) / BIN_T, 512, 0, stream>>>(src, dst, bdst, bsrc, gcnt, E, cap);
    scan_gcnt<<<1, 64, 0, stream>>>(gcnt, gbase, row_start, N, E);
    csr_bucket<<<nbuk, 256, 0, stream>>>(bdst, bsrc, gcnt, gbase, row_start, csr, cap, N);

    // ---- conversions + weight transposes (one dispatch) ----
    {
        int n4 = N * 256 / 4;
        int nConv = (n4 + 255) / 256;
        conv_wt_kernel<<<nConv + 1152, 256, 0, stream>>>(
            x, xb, x8, H08, n4, nConv, Ws0, Wn0, Ws1, Wn1, Ws2, Wn2, Wt0, Wt1, Wt2);
    }

    dim3 agg256Grid((N + 15) / 16);            // 4 nodes/wave, 4 waves/block
    dim3 agg64Grid((N + 31) / 32);             // 8 nodes/wave, 4 waves/block
    dim3 gStripe((N + BTM - 1) / BTM);         // 391 blocks x 512 thr
    dim3 gL2((N + TM - 1) / TM);               // 391 (both halves fused)

    // ---- layer 0 ----
    agg256_fp8<<<agg256Grid, 256, 0, stream>>>(x8, row_start, csr, A1b, N, N);
    gemm_big512<<<gStripe, 512, 0, stream>>>(xb, A1b, Wt0, b0, nullptr, H0b, H08, N);
    // ---- layer 1 ----
    agg256_fp8<<<agg256Grid, 256, 0, stream>>>(H08, row_start, csr, A1b, N, N);
    gemm_big512<<<gStripe, 512, 0, stream>>>(H0b, A1b, Wt1, b1, h1, h1b, nullptr, N);
    // ---- layer 2: stacked gemm (both halves) + fused aggregate/add ----
    gemm_l2<<<gL2, 256, 0, stream>>>(h1b, Wt2, Sself, Tb, N);
    agg64_final<<<agg64Grid, 256, 0, stream>>>(Tb, row_start, csr, Sself, b2, h2, N);
}

// Round 10
// 435.338 us; speedup vs baseline: 1.0803x; 1.0803x over previous
//
#include <hip/hip_runtime.h>
#include <hip/hip_bf16.h>
#include <cstdint>

// ---------------------------------------------------------------------------
// GraphSAGE inference. bf16 GEMM plane (MFMA, async LDS staging); fp8 e4m3
// aggregation tables; node-range-binned CSR build.
// Round 17: ALIGNMENT FIX. R9's workspace reshuffle left the 256B-row fp8
// tables 64B-aligned -> each row spanned 3 cache lines (FETCH x1.5, agg256
// 56->71us). All workspace regions now padded to 256B. Structure = R16:
// fused CSR (bin -> scan_gcnt -> csr_bucket), merged conv+wt, single-pass
// gemm_l2, R7-config gemm_big512. nt stores only on true sinks (h1, h2).
// ---------------------------------------------------------------------------

typedef __attribute__((ext_vector_type(8))) short  frag_ab;  // 8 bf16
typedef __attribute__((ext_vector_type(4))) float  f32x4;
typedef __attribute__((ext_vector_type(2))) float  vf2;

#define BIN_T 4096      // edges per partition tile (512 thr x 8)
#define RSHIFT 9        // 512-node bucket ranges
#define RW 512

__device__ __forceinline__ unsigned short f2b(float f) {
    __hip_bfloat16 h = __float2bfloat16(f);
    return *reinterpret_cast<unsigned short*>(&h);
}
__device__ __forceinline__ unsigned char f2p8(float f) {
    int p = __builtin_amdgcn_cvt_pk_fp8_f32(f, f, 0, false);
    return (unsigned char)(p & 0xff);
}
// accumulate 8 bf16 (as uint4) into 4 packed-f32 pairs
__device__ __forceinline__ void acc8_v(vf2* a, uint4 v) {
    vf2 t0; t0.x = __uint_as_float(v.x << 16); t0.y = __uint_as_float(v.x & 0xffff0000u);
    vf2 t1; t1.x = __uint_as_float(v.y << 16); t1.y = __uint_as_float(v.y & 0xffff0000u);
    vf2 t2; t2.x = __uint_as_float(v.z << 16); t2.y = __uint_as_float(v.z & 0xffff0000u);
    vf2 t3; t3.x = __uint_as_float(v.w << 16); t3.y = __uint_as_float(v.w & 0xffff0000u);
    a[0] += t0; a[1] += t1; a[2] += t2; a[3] += t3;
}
// accumulate 16 fp8 (as uint4) into 8 packed-f32 pairs via HW cvt
__device__ __forceinline__ void acc16p_v(vf2* a, uint4 v) {
    a[0] += __builtin_amdgcn_cvt_pk_f32_fp8(v.x, false);
    a[1] += __builtin_amdgcn_cvt_pk_f32_fp8(v.x, true);
    a[2] += __builtin_amdgcn_cvt_pk_f32_fp8(v.y, false);
    a[3] += __builtin_amdgcn_cvt_pk_f32_fp8(v.y, true);
    a[4] += __builtin_amdgcn_cvt_pk_f32_fp8(v.z, false);
    a[5] += __builtin_amdgcn_cvt_pk_f32_fp8(v.z, true);
    a[6] += __builtin_amdgcn_cvt_pk_f32_fp8(v.w, false);
    a[7] += __builtin_amdgcn_cvt_pk_f32_fp8(v.w, true);
}

// async global->LDS, 16B per lane; lds base wave-uniform (HW adds lane*16)
__device__ __forceinline__ void gl_lds16(const void* g, void* l) {
    __builtin_amdgcn_global_load_lds(
        (const __attribute__((address_space(1))) unsigned int*)g,
        (__attribute__((address_space(3))) unsigned int*)l, 16, 0, 0);
}

// ---------------- CSR build: node-range binning ----------------
__global__ __launch_bounds__(512) void bin_edges(
    const int* __restrict__ src, const int* __restrict__ dst,
    int* __restrict__ bdst, int* __restrict__ bsrc,
    int* __restrict__ gcnt, int E, int cap) {
    __shared__ int lds_d[BIN_T];
    __shared__ int lds_s[BIN_T];
    __shared__ unsigned short lds_b[BIN_T];
    __shared__ int hist[8][128];
    __shared__ int cur[8][128];
    __shared__ int tot[128], scn[128], pref[128], gbase[128];

    const int tid = threadIdx.x;
    const int w = tid >> 6;
    const int e0 = blockIdx.x * BIN_T;
    const int base = e0 + tid * 8;

    int d[8], sv[8], bk[8];
    if (e0 + BIN_T <= E) {
        int4 a0 = *reinterpret_cast<const int4*>(dst + base);
        int4 a1 = *reinterpret_cast<const int4*>(dst + base + 4);
        int4 b0 = *reinterpret_cast<const int4*>(src + base);
        int4 b1 = *reinterpret_cast<const int4*>(src + base + 4);
        d[0] = a0.x; d[1] = a0.y; d[2] = a0.z; d[3] = a0.w;
        d[4] = a1.x; d[5] = a1.y; d[6] = a1.z; d[7] = a1.w;
        sv[0] = b0.x; sv[1] = b0.y; sv[2] = b0.z; sv[3] = b0.w;
        sv[4] = b1.x; sv[5] = b1.y; sv[6] = b1.z; sv[7] = b1.w;
#pragma unroll
        for (int j = 0; j < 8; j++) bk[j] = (int)((unsigned)d[j] >> RSHIFT);
    } else {
#pragma unroll
        for (int j = 0; j < 8; j++) {
            int e = base + j;
            if (e < E) {
                d[j] = dst[e]; sv[j] = src[e];
                bk[j] = (int)((unsigned)d[j] >> RSHIFT);
            } else {
                d[j] = 0; sv[j] = 0; bk[j] = -1;
            }
        }
    }

    // zero histograms
    for (int i = tid; i < 8 * 128; i += 512) ((int*)hist)[i] = 0;
    __syncthreads();
    // per-wave LDS histogram (contention ~ BIN_T/8/98 ~= 5)
#pragma unroll
    for (int j = 0; j < 8; j++)
        if (bk[j] >= 0) atomicAdd(&hist[w][bk[j]], 1);
    __syncthreads();
    // bucket totals + exclusive prefix (Hillis-Steele over 128)
    if (tid < 128) {
        int t = 0;
#pragma unroll
        for (int w2 = 0; w2 < 8; w2++) t += hist[w2][tid];
        tot[tid] = t; scn[tid] = t;
    }
    __syncthreads();
#pragma unroll
    for (int off = 1; off < 128; off <<= 1) {
        int v = 0;
        if (tid < 128 && tid >= off) v = scn[tid - off];
        __syncthreads();
        if (tid < 128 && tid >= off) scn[tid] += v;
        __syncthreads();
    }
    if (tid < 128) {
        pref[tid] = scn[tid] - tot[tid];
        gbase[tid] = atomicAdd(&gcnt[tid], tot[tid]);
        int b0 = pref[tid];
#pragma unroll
        for (int w2 = 0; w2 < 8; w2++) { cur[w2][tid] = b0; b0 += hist[w2][tid]; }
    }
    __syncthreads();
    // ranked placement into LDS
#pragma unroll
    for (int j = 0; j < 8; j++) {
        if (bk[j] >= 0) {
            int pos = atomicAdd(&cur[w][bk[j]], 1);
            lds_d[pos] = d[j];
            lds_s[pos] = sv[j];
            lds_b[pos] = (unsigned short)bk[j];
        }
    }
    __syncthreads();
    // coalesced flush
    const int nv = scn[127];
    for (int i = tid; i < nv; i += 512) {
        int b = lds_b[i];
        int off = gbase[b] + (i - pref[b]);
        bdst[(size_t)b * cap + off] = lds_d[i];
        bsrc[(size_t)b * cap + off] = lds_s[i];
    }
}

// One wave: exclusive scan of gcnt[128] -> gbase[128]; row_start[N] = E.
__global__ void scan_gcnt(const int* __restrict__ gcnt, int* __restrict__ gbase,
                          int* __restrict__ row_start, int N, int E) {
    const int lane = threadIdx.x;  // 64
    int v0 = gcnt[lane];
    int v1 = gcnt[64 + lane];
    int s0 = v0;
#pragma unroll
    for (int off = 1; off < 64; off <<= 1) { int x = __shfl_up(s0, off); if (lane >= off) s0 += x; }
    int tot0 = __shfl(s0, 63);
    int s1 = v1;
#pragma unroll
    for (int off = 1; off < 64; off <<= 1) { int x = __shfl_up(s1, off); if (lane >= off) s1 += x; }
    gbase[lane] = s0 - v0;
    gbase[64 + lane] = tot0 + s1 - v1;
    if (lane == 0) row_start[N] = E;
}

// Fused per-bucket: histogram -> 512-entry LDS scan -> row_start write ->
// scatter into csr (bucket-private ~65KB span, L2 write-combined).
__global__ __launch_bounds__(256) void csr_bucket(
    const int* __restrict__ bdst, const int* __restrict__ bsrc,
    const int* __restrict__ gcnt, const int* __restrict__ gbase,
    int* __restrict__ row_start, int* __restrict__ csr, int cap, int N) {
    const int b = blockIdx.x;
    const int cnt = gcnt[b];
    const int base = gbase[b];
    const int v0 = b << RSHIFT;
    __shared__ int h[RW];
    __shared__ int scn[RW];
    __shared__ int cur[RW];
    for (int k = threadIdx.x; k < RW; k += 256) h[k] = 0;
    __syncthreads();
    const int* bd = bdst + (size_t)b * cap;
    for (int i = threadIdx.x; i < cnt; i += 256)
        atomicAdd(&h[bd[i] & (RW - 1)], 1);
    __syncthreads();
    for (int k = threadIdx.x; k < RW; k += 256) scn[k] = h[k];
    __syncthreads();
    // inclusive Hillis-Steele over 512 with 256 threads (2 elems/thread)
    const int k0 = threadIdx.x, k1 = threadIdx.x + 256;
#pragma unroll
    for (int off = 1; off < RW; off <<= 1) {
        int t0 = (k0 >= off) ? scn[k0 - off] : 0;
        int t1 = (k1 >= off) ? scn[k1 - off] : 0;
        __syncthreads();
        scn[k0] += t0;
        scn[k1] += t1;
        __syncthreads();
    }
    for (int k = threadIdx.x; k < RW; k += 256) {
        int ex = base + scn[k] - h[k];     // exclusive prefix
        cur[k] = ex;
        int node = v0 + k;
        if (node < N) row_start[node] = ex;
    }
    __syncthreads();
    const int* bs = bsrc + (size_t)b * cap;
    for (int i = threadIdx.x; i < cnt; i += 256) {
        int dd = bd[i];
        int ss = bs[i];
        int pos = atomicAdd(&cur[dd & (RW - 1)], 1);
        csr[pos] = ss;
    }
}

// ---------------- conversions (merged conv_x + wt_all) ----------------
// Blocks [0, nConv): x -> bf16 + fp8 (+ zero rows of both fp8 tables).
// Blocks [nConv, nConv+1152): weight transposes.
__global__ __launch_bounds__(256) void conv_wt_kernel(
    const float* __restrict__ in, unsigned short* __restrict__ outb,
    unsigned char* __restrict__ outp, unsigned char* __restrict__ outp2, int n4, int nConv,
    const float* __restrict__ Ws0, const float* __restrict__ Wn0,
    const float* __restrict__ Ws1, const float* __restrict__ Wn1,
    const float* __restrict__ Ws2, const float* __restrict__ Wn2,
    unsigned short* __restrict__ Wt0, unsigned short* __restrict__ Wt1,
    unsigned short* __restrict__ Wt2) {
    if (blockIdx.x < (unsigned)nConv) {
        int i = blockIdx.x * 256 + threadIdx.x;
        if (blockIdx.x == 0 && threadIdx.x < 64) {
            *reinterpret_cast<unsigned int*>(outp  + (size_t)n4 * 4 + threadIdx.x * 4) = 0u;
            *reinterpret_cast<unsigned int*>(outp2 + (size_t)n4 * 4 + threadIdx.x * 4) = 0u;
        }
        if (i >= n4) return;
        float4 v = *reinterpret_cast<const float4*>(in + (size_t)i * 4);
        ushort4 ob = { f2b(v.x), f2b(v.y), f2b(v.z), f2b(v.w) };
        *reinterpret_cast<ushort4*>(outb + (size_t)i * 4) = ob;
        int p0 = __builtin_amdgcn_cvt_pk_fp8_f32(v.x, v.y, 0, false);
        int p1 = __builtin_amdgcn_cvt_pk_fp8_f32(v.z, v.w, 0, false);
        unsigned int packed = (unsigned int)(p0 & 0xffff) | ((unsigned int)p1 << 16);
        *reinterpret_cast<unsigned int*>(outp + (size_t)i * 4) = packed;
        return;
    }
    int b = blockIdx.x - nConv;
    const float* W; unsigned short* Wt; int Nn, koff, Ktot, noff, idx;
    if (b < 1024) {
        int seg = b >> 8; idx = (b & 255) * 256 + threadIdx.x;
        Nn = 256; Ktot = 512; noff = 0;
        if (seg == 0)      { W = Ws0; Wt = Wt0; koff = 0;   }
        else if (seg == 1) { W = Wn0; Wt = Wt0; koff = 256; }
        else if (seg == 2) { W = Ws1; Wt = Wt1; koff = 0;   }
        else               { W = Wn1; Wt = Wt1; koff = 256; }
    } else {
        int seg = (b - 1024) >> 6; idx = ((b - 1024) & 63) * 256 + threadIdx.x;
        Nn = 64; Ktot = 256; koff = 0;
        if (seg == 0) { W = Ws2; Wt = Wt2; noff = 0;  }
        else          { W = Wn2; Wt = Wt2; noff = 64; }
    }
    int k = idx / Nn, n = idx - k * Nn;
    Wt[(size_t)(n + noff) * Ktot + koff + k] = f2b(W[(size_t)idx]);
}

// ---------------- aggregation ----------------
// fp8 rows (256B). One node per 16-lane quarter; lane owns 16B slice.
// Sequential edge stream, 6-deep modulo-scheduled prefetch; OOB -> zero row.
__global__ __launch_bounds__(256) void agg256_fp8(
    const unsigned char* __restrict__ hsrc, const int* __restrict__ row_start,
    const int* __restrict__ csr, unsigned short* __restrict__ out, int n, int zrow) {
    int wv = (blockIdx.x * blockDim.x + threadIdx.x) >> 6;
    int lane = threadIdx.x & 63;
    if (wv * 4 >= n) return;
    const int q  = lane >> 4;
    const int li = lane & 15;
    const int node = wv * 4 + q;
    const bool act = node < n;
    int s0 = act ? row_start[node] : 0;
    int s1 = act ? row_start[node + 1] : 0;
    int deg = s1 - s0;
    int nmax = deg;
    nmax = max(nmax, __shfl_xor(nmax, 16));
    nmax = max(nmax, __shfl_xor(nmax, 32));

    const size_t lioff = (size_t)li * 16;
    vf2 a[8];
#pragma unroll
    for (int k = 0; k < 8; k++) a[k] = (vf2)(0.f);

#define LD256(vv, k) { int _e = s0 + (k); \
    int _ci = csr[max(min(_e, s1 - 1), 0)]; \
    int _ii = ((k) < deg) ? _ci : zrow; \
    vv = *reinterpret_cast<const uint4*>(hsrc + (size_t)_ii * 256 + lioff); }

    uint4 v0, v1, v2, v3, v4, v5;
    LD256(v0, 0); LD256(v1, 1); LD256(v2, 2);
    LD256(v3, 3); LD256(v4, 4); LD256(v5, 5);
    for (int b = 0; b < nmax; b += 6) {
        acc16p_v(a, v0); LD256(v0, b + 6);
        acc16p_v(a, v1); LD256(v1, b + 7);
        acc16p_v(a, v2); LD256(v2, b + 8);
        acc16p_v(a, v3); LD256(v3, b + 9);
        acc16p_v(a, v4); LD256(v4, b + 10);
        acc16p_v(a, v5); LD256(v5, b + 11);
    }
#undef LD256

    if (act) {
        float sc = 1.0f / (float)max(deg, 1);
        uint4 o0, o1;
        o0.x = ((unsigned)f2b(a[0].y * sc) << 16) | f2b(a[0].x * sc);
        o0.y = ((unsigned)f2b(a[1].y * sc) << 16) | f2b(a[1].x * sc);
        o0.z = ((unsigned)f2b(a[2].y * sc) << 16) | f2b(a[2].x * sc);
        o0.w = ((unsigned)f2b(a[3].y * sc) << 16) | f2b(a[3].x * sc);
        o1.x = ((unsigned)f2b(a[4].y * sc) << 16) | f2b(a[4].x * sc);
        o1.y = ((unsigned)f2b(a[5].y * sc) << 16) | f2b(a[5].x * sc);
        o1.z = ((unsigned)f2b(a[6].y * sc) << 16) | f2b(a[6].x * sc);
        o1.w = ((unsigned)f2b(a[7].y * sc) << 16) | f2b(a[7].x * sc);
        *reinterpret_cast<uint4*>(out + (size_t)node * 256 + li * 16) = o0;
        *reinterpret_cast<uint4*>(out + (size_t)node * 256 + li * 16 + 8) = o1;
    }
}

// h2[v][:] = Sself[v][:] + mean_{s in N(v)} Tb[s][:] + b2 ; Tb bf16 64-wide.
// One node per 8-lane group; lane owns 16B (8 bf16) slice; 6-deep prefetch.
// OOB edges zeroed in-register. h2 is a final sink -> nontemporal store.
__global__ __launch_bounds__(256) void agg64_final(
    const unsigned short* __restrict__ t, const int* __restrict__ row_start,
    const int* __restrict__ csr, const float* __restrict__ Sself,
    const float* __restrict__ b2, float* __restrict__ h2, int n) {
    int wv = (blockIdx.x * blockDim.x + threadIdx.x) >> 6;
    int lane = threadIdx.x & 63;
    if (wv * 8 >= n) return;
    const int g  = lane >> 3;
    const int li = lane & 7;
    const int node = wv * 8 + g;
    const bool act = node < n;
    int s0 = act ? row_start[node] : 0;
    int s1 = act ? row_start[node + 1] : 0;
    int deg = s1 - s0;
    int nmax = deg;
    nmax = max(nmax, __shfl_xor(nmax, 8));
    nmax = max(nmax, __shfl_xor(nmax, 16));
    nmax = max(nmax, __shfl_xor(nmax, 32));

    const size_t lioff = (size_t)li * 8;   // shorts
    vf2 a[4];
#pragma unroll
    for (int k = 0; k < 4; k++) a[k] = (vf2)(0.f);

#define LD64(vv, k) { int _e = s0 + (k); \
    int _ci = csr[max(min(_e, s1 - 1), 0)]; \
    vv = make_uint4(0u, 0u, 0u, 0u); \
    if ((k) < deg) \
        vv = *reinterpret_cast<const uint4*>(t + (size_t)_ci * 64 + lioff); }

    uint4 v0, v1, v2, v3, v4, v5;
    LD64(v0, 0); LD64(v1, 1); LD64(v2, 2);
    LD64(v3, 3); LD64(v4, 4); LD64(v5, 5);
    for (int b = 0; b < nmax; b += 6) {
        acc8_v(a, v0); LD64(v0, b + 6);
        acc8_v(a, v1); LD64(v1, b + 7);
        acc8_v(a, v2); LD64(v2, b + 8);
        acc8_v(a, v3); LD64(v3, b + 9);
        acc8_v(a, v4); LD64(v4, b + 10);
        acc8_v(a, v5); LD64(v5, b + 11);
    }
#undef LD64

    if (act) {
        float sc = 1.0f / (float)max(deg, 1);
        float4 s0v = *reinterpret_cast<const float4*>(Sself + (size_t)node * 64 + li * 8);
        float4 s1v = *reinterpret_cast<const float4*>(Sself + (size_t)node * 64 + li * 8 + 4);
        float4 bb0 = *reinterpret_cast<const float4*>(b2 + li * 8);
        float4 bb1 = *reinterpret_cast<const float4*>(b2 + li * 8 + 4);
        f32x4 o0, o1;
        o0.x = s0v.x + a[0].x * sc + bb0.x; o0.y = s0v.y + a[0].y * sc + bb0.y;
        o0.z = s0v.z + a[1].x * sc + bb0.z; o0.w = s0v.w + a[1].y * sc + bb0.w;
        o1.x = s1v.x + a[2].x * sc + bb1.x; o1.y = s1v.y + a[2].y * sc + bb1.y;
        o1.z = s1v.z + a[3].x * sc + bb1.z; o1.w = s1v.w + a[3].y * sc + bb1.w;
        __builtin_nontemporal_store(o0, reinterpret_cast<f32x4*>(h2 + (size_t)node * 64 + li * 8));
        __builtin_nontemporal_store(o1, reinterpret_cast<f32x4*>(h2 + (size_t)node * 64 + li * 8 + 4));
    }
}

// ---------------- big GEMM: 128x256 row-stripe, 512 threads ----------------
// C[M,256] = relu( [A|G] @ Wt^T + bias ); A,G bf16 [M][256], Wt bf16 [256][512].
#define BTM 128
#define BTN 256
#define BTK 32

__global__ __launch_bounds__(512, 4) void gemm_big512(
    const unsigned short* __restrict__ A, const unsigned short* __restrict__ G,
    const unsigned short* __restrict__ Wt, const float* __restrict__ bias,
    float* __restrict__ outF, unsigned short* __restrict__ outB,
    unsigned char* __restrict__ outP, int M) {
    __shared__ unsigned short Asb[BTM][BTK];   // 8 KB, lane-linear for lds-dma
    __shared__ unsigned short Bsb[BTN][BTK];   // 16 KB

    const int tid = threadIdx.x;
    const int row0 = blockIdx.x * BTM;
    const int w = tid >> 6, lane = tid & 63;
    const int mw = (w & 1) * 64;       // wave m-offset (2 m-groups)
    const int nw = (w >> 1) * 64;      // wave n-offset (4 n-groups)
    const int lm = lane & 15, lq = lane >> 4;
    const int lr = lane >> 2;          // 0..15
    const int lc = (lane & 3) * 8;     // 0/8/16/24 shorts

    f32x4 acc[4][4];
#pragma unroll
    for (int i = 0; i < 4; i++)
#pragma unroll
        for (int j = 0; j < 4; j++) acc[i][j] = (f32x4)(0.f);

    for (int k0 = 0; k0 < 512; k0 += BTK) {
        const unsigned short* __restrict__ Ap = (k0 >= 256) ? G : A;
        const int kl = k0 & 255;
        {
            int gr = row0 + w * 16 + lr;
            if (gr < M)
                gl_lds16(Ap + (size_t)gr * 256 + kl + lc, &Asb[w * 16][0]);
        }
#pragma unroll
        for (int h = 0; h < 2; ++h) {
            int gn = w * 32 + h * 16 + lr;
            gl_lds16(Wt + (size_t)gn * 512 + k0 + lc, &Bsb[w * 32 + h * 16][0]);
        }
        __syncthreads();

        frag_ab a[4], b[4];
#pragma unroll
        for (int i = 0; i < 4; i++)
            a[i] = *reinterpret_cast<const frag_ab*>(&Asb[mw + i * 16 + lm][lq * 8]);
#pragma unroll
        for (int j = 0; j < 4; j++)
            b[j] = *reinterpret_cast<const frag_ab*>(&Bsb[nw + j * 16 + lm][lq * 8]);
#pragma unroll
        for (int i = 0; i < 4; i++)
#pragma unroll
            for (int j = 0; j < 4; j++)
                acc[i][j] = __builtin_amdgcn_mfma_f32_16x16x32_bf16(a[i], b[j], acc[i][j], 0, 0, 0);
        __syncthreads();
    }

#pragma unroll
    for (int i = 0; i < 4; i++) {
#pragma unroll
        for (int j = 0; j < 4; j++) {
            int cg = nw + j * 16 + lm;
#pragma unroll
            for (int r = 0; r < 4; r++) {
                int rg = row0 + mw + i * 16 + lq * 4 + r;
                if (rg >= M) continue;
                float v = acc[i][j][r] + bias[cg];
                v = fmaxf(v, 0.f);
                outB[(size_t)rg * 256 + cg] = f2b(v);
                if (outF) __builtin_nontemporal_store(v, &outF[(size_t)rg * 256 + cg]);  // h1 = final sink
                if (outP) outP[(size_t)rg * 256 + cg] = f2p8(v);
            }
        }
    }
}

// ---------------- layer-2 GEMM: TN=128, both halves in one pass ------------
// Sself (cols 0-63, fp32) | Tb (cols 64-127, bf16). h1b read ONCE.
#define TM 128

__global__ __launch_bounds__(256) void gemm_l2(
    const unsigned short* __restrict__ A, const unsigned short* __restrict__ Wt,
    float* __restrict__ outF, unsigned short* __restrict__ outB, int M) {
    __shared__ unsigned short Asb[128][32];    // 8 KB
    __shared__ unsigned short Bsb[128][32];    // 8 KB

    const int tid = threadIdx.x;
    const int row0 = blockIdx.x * TM;
    const int w = tid >> 6, lane = tid & 63;
    const int mw = (w & 1) * 64;
    const int nw = (w >> 1) * 64;
    const int lm = lane & 15, lq = lane >> 4;
    const int lr = lane >> 2;
    const int lc = (lane & 3) * 8;

    f32x4 acc[4][4];
#pragma unroll
    for (int i = 0; i < 4; i++)
#pragma unroll
        for (int j = 0; j < 4; j++) acc[i][j] = (f32x4)(0.f);

    for (int k0 = 0; k0 < 256; k0 += 32) {
#pragma unroll
        for (int h = 0; h < 2; ++h) {
            int r16 = w * 32 + h * 16;
            int gr = row0 + r16 + lr;
            if (gr < M)
                gl_lds16(A + (size_t)gr * 256 + k0 + lc, &Asb[r16][0]);
        }
#pragma unroll
        for (int h = 0; h < 2; ++h) {
            int n16 = w * 32 + h * 16;
            int gn = n16 + lr;
            gl_lds16(Wt + (size_t)gn * 256 + k0 + lc, &Bsb[n16][0]);
        }
        __syncthreads();

        frag_ab a[4], b[4];
#pragma unroll
        for (int i = 0; i < 4; i++)
            a[i] = *reinterpret_cast<const frag_ab*>(&Asb[mw + i * 16 + lm][lq * 8]);
#pragma unroll
        for (int j = 0; j < 4; j++)
            b[j] = *reinterpret_cast<const frag_ab*>(&Bsb[nw + j * 16 + lm][lq * 8]);
#pragma unroll
        for (int i = 0; i < 4; i++)
#pragma unroll
            for (int j = 0; j < 4; j++)
                acc[i][j] = __builtin_amdgcn_mfma_f32_16x16x32_bf16(a[i], b[j], acc[i][j], 0, 0, 0);
        __syncthreads();
    }

#pragma unroll
    for (int i = 0; i < 4; i++) {
#pragma unroll
        for (int j = 0; j < 4; j++) {
            int cg = nw + j * 16 + lm;   // 0..127
#pragma unroll
            for (int r = 0; r < 4; r++) {
                int rg = row0 + mw + i * 16 + lq * 4 + r;
                if (rg >= M) continue;
                float v = acc[i][j][r];
                if (cg < 64) outF[(size_t)rg * 64 + cg] = v;
                else         outB[(size_t)rg * 64 + (cg - 64)] = f2b(v);
            }
        }
    }
}

// ---------------------------------------------------------------------------
extern "C" void kernel_launch(void* const* d_in, const int* in_sizes, int n_in,
                              void* d_out, int out_size, void* d_ws, size_t ws_size,
                              hipStream_t stream) {
    const float* x   = (const float*)d_in[0];
    const int*   src = (const int*)d_in[1];
    const int*   dst = (const int*)d_in[2];
    const float* Ws0 = (const float*)d_in[3];
    const float* Wn0 = (const float*)d_in[4];
    const float* b0  = (const float*)d_in[5];
    const float* Ws1 = (const float*)d_in[6];
    const float* Wn1 = (const float*)d_in[7];
    const float* b1  = (const float*)d_in[8];
    const float* Ws2 = (const float*)d_in[9];
    const float* Wn2 = (const float*)d_in[10];
    const float* b2  = (const float*)d_in[11];

    const int N = in_sizes[0] / 256;   // 50000
    const int E = in_sizes[1];         // 1600000

    float* out = (float*)d_out;
    float* h2 = out;                       // N x 64  (output 0)
    float* h1 = out + (size_t)N * 64;      // N x 256 (output 1, fp32)

    const int nbuk = (N + RW - 1) >> RSHIFT;              // 98
    const int cap  = (E + nbuk - 1) / nbuk + 2048;        // mean + ~16 sigma

    // ---- workspace layout (EVERY region padded to 256B so the 256B-row
    //      gather tables stay 128B-line aligned — R9 lesson) ----
    char* w = (char*)d_ws;
    auto take = [&w](size_t bytes) {
        char* p = w;
        w += (bytes + 255) & ~(size_t)255;
        return p;
    };
    int* gcnt      = (int*)take(128 * 4);
    int* gbase     = (int*)take(128 * 4);
    int* row_start = (int*)take((size_t)(N + 1) * 4);
    int* csr       = (int*)take((size_t)E * 4);
    int* bdst      = (int*)take((size_t)nbuk * cap * 4);
    int* bsrc      = (int*)take((size_t)nbuk * cap * 4);
    unsigned short* Wt0 = (unsigned short*)take((size_t)256 * 512 * 2);
    unsigned short* Wt1 = (unsigned short*)take((size_t)256 * 512 * 2);
    unsigned short* Wt2 = (unsigned short*)take((size_t)128 * 256 * 2);  // [Ws2t;Wn2t]
    unsigned short* xb  = (unsigned short*)take((size_t)(N + 1) * 256 * 2);
    unsigned short* A1b = (unsigned short*)take((size_t)N * 256 * 2);
    unsigned short* H0b = (unsigned short*)take((size_t)(N + 1) * 256 * 2);
    unsigned short* h1b = (unsigned short*)take((size_t)(N + 1) * 256 * 2);
    // dead-region aliases (zero extra workspace):
    unsigned char* x8  = (unsigned char*)H0b;  // dead once gemm0 writes H0b
    unsigned char* H08 = (unsigned char*)h1b;  // consumed by agg#2 before gemm1 writes h1b
    unsigned short* Tb    = xb;                // xb dead after gemm0
    float*          Sself = (float*)A1b;       // A1b dead after gemm1

    // ---- CSR build: bin -> scan -> fused bucket (hist+scan+rowstart+scatter)
    hipMemsetAsync(gcnt, 0, 128 * 4, stream);
    bin_edges<<<(E + BIN_T - 1) / BIN_T, 512, 0, stream>>>(src, dst, bdst, bsrc, gcnt, E, cap);
    scan_gcnt<<<1, 64, 0, stream>>>(gcnt, gbase, row_start, N, E);
    csr_bucket<<<nbuk, 256, 0, stream>>>(bdst, bsrc, gcnt, gbase, row_start, csr, cap, N);

    // ---- conversions + weight transposes (one dispatch) ----
    {
        int n4 = N * 256 / 4;
        int nConv = (n4 + 255) / 256;
        conv_wt_kernel<<<nConv + 1152, 256, 0, stream>>>(
            x, xb, x8, H08, n4, nConv, Ws0, Wn0, Ws1, Wn1, Ws2, Wn2, Wt0, Wt1, Wt2);
    }

    dim3 agg256Grid((N + 15) / 16);            // 4 nodes/wave, 4 waves/block
    dim3 agg64Grid((N + 31) / 32);             // 8 nodes/wave, 4 waves/block
    dim3 gStripe((N + BTM - 1) / BTM);         // 391 blocks x 512 thr
    dim3 gL2((N + TM - 1) / TM);               // 391 (both halves fused)

    // ---- layer 0 ----
    agg256_fp8<<<agg256Grid, 256, 0, stream>>>(x8, row_start, csr, A1b, N, N);
    gemm_big512<<<gStripe, 512, 0, stream>>>(xb, A1b, Wt0, b0, nullptr, H0b, H08, N);
    // ---- layer 1 ----
    agg256_fp8<<<agg256Grid, 256, 0, stream>>>(H08, row_start, csr, A1b, N, N);
    gemm_big512<<<gStripe, 512, 0, stream>>>(H0b, A1b, Wt1, b1, h1, h1b, nullptr, N);
    // ---- layer 2: stacked gemm (both halves) + fused aggregate/add ----
    gemm_l2<<<gL2, 256, 0, stream>>>(h1b, Wt2, Sself, Tb, N);
    agg64_final<<<agg64Grid, 256, 0, stream>>>(Tb, row_start, csr, Sself, b2, h2, N);
}